// Round 10
// baseline (353.623 us; speedup 1.0000x reference)
//
#include <hip/hip_runtime.h>

// Attention_22325240004782 — additive attention. B=64, L=196, D=2048, A=1024.
// R10: R8's fused-conversion GEMM with the root-cause fix: __launch_bounds__
// (512,1). LDS already limits to 1 block/CU; the old (512,2) capped VGPR at
// 128 and forced 579 MB of spill. No conv pass; prep = transpose + ph only.

typedef unsigned short u16;
typedef u16 u16x8 __attribute__((ext_vector_type(8)));
typedef __bf16 bf16x8 __attribute__((ext_vector_type(8)));
typedef float f32x4 __attribute__((ext_vector_type(4)));

#define B_ 64
#define L_ 196
#define D_ 2048
#define A_ 1024
#define M_ (B_ * L_)  // 12544 = 49 * 256

__device__ __forceinline__ u16 f2bf(float x) {
  unsigned u = __float_as_uint(x);
  unsigned r = (u + 0x7fffu + ((u >> 16) & 1u)) >> 16;  // RNE
  return (u16)r;
}

__device__ __forceinline__ float tanh_fast(float x) {
  float e = __expf(2.0f * x);
  return 1.0f - 2.0f / (e + 1.0f);
}

__device__ __forceinline__ void gload_lds16(const void* g, void* l) {
  __builtin_amdgcn_global_load_lds(
      (const __attribute__((address_space(1))) void*)g,
      (__attribute__((address_space(3))) void*)l, 16, 0, 0);
}

// ---- fused prep: [0,256) ph split-K | [256,2304) W_att transpose ----
__global__ __launch_bounds__(256) void prep_k(
    const float* __restrict__ W, u16* __restrict__ WT,
    const float* __restrict__ h, const float* __restrict__ Wh,
    float* __restrict__ ph) {
  __shared__ float smem[2112];
  const int bid = blockIdx.x;
  const int t = threadIdx.x;
  if (bid < 256) {  // ph split-K (256-iter inner loop, atomics)
    const int ag = bid & 3, bg = (bid >> 2) & 7, dc = bid >> 5;
    const int d0 = dc * 256;
    for (int i = t; i < 2048; i += 256)
      smem[i] = h[(size_t)(bg * 8 + (i >> 8)) * D_ + d0 + (i & 255)];
    __syncthreads();
    const int a = ag * 256 + t;
    float acc[8] = {};
#pragma unroll 8
    for (int d = 0; d < 256; ++d) {
      float wv = Wh[(size_t)(d0 + d) * A_ + a];
#pragma unroll
      for (int bb = 0; bb < 8; ++bb) acc[bb] += smem[bb * 256 + d] * wv;
    }
#pragma unroll
    for (int bb = 0; bb < 8; ++bb)
      atomicAdd(&ph[(size_t)(bg * 8 + bb) * A_ + a], acc[bb]);
  } else {  // W_att [D][A] -> WT [A][D] bf16
    const int tb = bid - 256;
    const int n0 = (tb & 31) * 32, k0 = (tb >> 5) * 32;
    const int tx = t & 31, ty = t >> 5;
    float (*tt)[33] = (float (*)[33])smem;
#pragma unroll
    for (int i = 0; i < 4; ++i)
      tt[ty + i * 8][tx] = W[(size_t)(k0 + ty + i * 8) * A_ + n0 + tx];
    __syncthreads();
#pragma unroll
    for (int i = 0; i < 4; ++i)
      WT[(size_t)(n0 + ty + i * 8) * D_ + k0 + tx] = f2bf(tt[tx][ty + i * 8]);
  }
}

// ==== 256x256x(BK=64) GEMM, fused fp32->bf16 A-staging + tanh-score epi ====
// 512 thr = 8 waves (2M x 4N). A: fp32 global -> regs (issue at tile start)
// -> cvt -> swizzled ds_write (one window later). B: gload_lds, pre-swizzled
// source. 3 barriers/tile. (512,1): LDS limits to 1 block/CU anyway; full
// 256-VGPR budget avoids R8's forced spill.
__global__ __launch_bounds__(512, 1) void gemm8_k(
    const float* __restrict__ af, const u16* __restrict__ WT,
    const float* __restrict__ ph, const float* __restrict__ batt,
    const float* __restrict__ bh, const float* __restrict__ walpha,
    float* __restrict__ scores4) {
  __shared__ __align__(16) u16 As[2][2][8192];
  __shared__ __align__(16) u16 Bs[2][2][8192];
  const int tid = threadIdx.x;
  const int lane = tid & 63;
  const int wid = tid >> 6;
  const int wr = wid >> 2;   // 0..1 (M)
  const int wc = wid & 3;    // 0..3 (N)
  const int wchalf = wc >> 1, wcl = wc & 1;
  const int fr = lane & 15, fq = lane >> 4;

  // bijective XCD remap: 196 blocks, q=24, r=4
  const int xcd = blockIdx.x & 7, idx = blockIdx.x >> 3;
  const int wg = (xcd < 4 ? xcd * 25 : 100 + (xcd - 4) * 24) + idx;
  const int m0 = (wg >> 2) * 256;
  const int n0 = (wg & 3) * 256;

  // ---- A reg-staging maps: 2048 chunks of 8 elems; 4 per thread ----
  // LDS dest (u16 idx) matches reader's laneA swizzle exactly.
  const float* aSrc[4];
  int aHh[4], aLds[4];
#pragma unroll
  for (int r = 0; r < 4; ++r) {
    const int c = r * 512 + tid;
    const int hh = c >> 10, cl = c & 1023;
    const int row = cl >> 3, cc = cl & 7;
    aHh[r] = hh;
    aSrc[r] = af + (size_t)(m0 + hh * 128 + row) * D_ + cc * 8;
    aLds[r] = ((row >> 4) * 2 + (cc >> 2)) * 512 + (row & 15) * 32 +
              (((cc & 3) * 8) ^ ((row & 8) << 1));
  }

  // ---- B staging geometry (pre-swizzled global source, linear LDS dest) ----
  int rowc[2], colc[2];
#pragma unroll
  for (int r = 0; r < 2; ++r) {
    int c = r * 512 + tid;
    int s = c >> 6, cw = c & 63;
    rowc[r] = (s >> 1) * 16 + (cw >> 2);
    colc[r] = (s & 1) * 32 + ((((cw & 3) * 16) ^ (((cw >> 5) & 1) * 32)) >> 1);
  }
  const u16* srcB[2][2];
#pragma unroll
  for (int hh = 0; hh < 2; ++hh)
#pragma unroll
    for (int r = 0; r < 2; ++r)
      srcB[hh][r] = WT + (size_t)(n0 + hh * 128 + rowc[r]) * D_ + colc[r];

  // swizzled lane byte offset for ds_read_b128 fragment reads
  const int laneA = (lane & 15) * 64 + (((lane >> 4) * 16) ^ ((lane & 8) << 2));

  f32x4 acc[8][4] = {};
  u16x8 areg[4][2], breg[4][2];

#define STG_B2(BUF, H, KT)                                                   \
  do {                                                                       \
    gload_lds16(srcB[H][0] + (size_t)(KT) * 64, &Bs[BUF][H][wid * 512]);     \
    gload_lds16(srcB[H][1] + (size_t)(KT) * 64, &Bs[BUF][H][4096 + wid * 512]); \
  } while (0)
#define LDA_HALF(BF, MH)                                                     \
  do {                                                                       \
    _Pragma("unroll") for (int q = 0; q < 4; ++q) {                          \
      areg[q][0] = *(const u16x8*)&As[BF][wr][((((MH)*4 + q) * 2 + 0) * 1024 + laneA) >> 1]; \
      areg[q][1] = *(const u16x8*)&As[BF][wr][((((MH)*4 + q) * 2 + 1) * 1024 + laneA) >> 1]; \
    }                                                                        \
  } while (0)
#define LDB_PAIR(BF, NQ)                                                     \
  do {                                                                       \
    _Pragma("unroll") for (int nn = 0; nn < 2; ++nn) {                       \
      breg[(NQ)*2 + nn][0] = *(const u16x8*)&Bs[BF][wchalf][(((wcl * 4 + (NQ)*2 + nn) * 2 + 0) * 1024 + laneA) >> 1]; \
      breg[(NQ)*2 + nn][1] = *(const u16x8*)&Bs[BF][wchalf][(((wcl * 4 + (NQ)*2 + nn) * 2 + 1) * 1024 + laneA) >> 1]; \
    }                                                                        \
  } while (0)
#define MM_QUAD(MH, NQ)                                                      \
  do {                                                                       \
    _Pragma("unroll") for (int q = 0; q < 4; ++q)                            \
    _Pragma("unroll") for (int nn = 0; nn < 2; ++nn)                         \
    _Pragma("unroll") for (int kh = 0; kh < 2; ++kh)                         \
      acc[(MH)*4 + q][(NQ)*2 + nn] = __builtin_amdgcn_mfma_f32_16x16x32_bf16( \
          __builtin_bit_cast(bf16x8, areg[q][kh]),                           \
          __builtin_bit_cast(bf16x8, breg[(NQ)*2 + nn][kh]),                 \
          acc[(MH)*4 + q][(NQ)*2 + nn], 0, 0, 0);                            \
  } while (0)
#define LGKM_BAR()                                                           \
  do {                                                                       \
    asm volatile("s_waitcnt lgkmcnt(0)" ::: "memory");                       \
    __builtin_amdgcn_s_barrier();                                            \
  } while (0)
// Tile t (BF=t&1), 3 barriers. Hazards:
//  - writes (DMA + ds_write) target buf^1, whose readers closed at t-1's end
//    barrier.
//  - cvt's a4 use: compiler inserts the vmcnt wait (register dependence).
//  - end vmcnt(0): B(t+1) DMA ~1 window old; lgkm0+barrier publishes A-writes.
#define TILE(BF, T, MODE)                                                    \
  do {                                                                       \
    float4 a4[4][2];                                                         \
    if ((MODE) == 0) {                                                       \
      _Pragma("unroll") for (int r = 0; r < 4; ++r) {                        \
        a4[r][0] = *(const float4*)(aSrc[r] + (size_t)((T) + 1) * 64);       \
        a4[r][1] = *(const float4*)(aSrc[r] + (size_t)((T) + 1) * 64 + 4);   \
      }                                                                      \
      STG_B2((BF) ^ 1, 0, (T) + 1);                                         \
      STG_B2((BF) ^ 1, 1, (T) + 1);                                         \
    }                                                                        \
    LDA_HALF(BF, 0); LDB_PAIR(BF, 0); LDB_PAIR(BF, 1);                       \
    LGKM_BAR();                                                              \
    __builtin_amdgcn_s_setprio(1);                                           \
    MM_QUAD(0, 0); MM_QUAD(0, 1);                                            \
    __builtin_amdgcn_s_setprio(0);                                           \
    LDA_HALF(BF, 1);                                                         \
    if ((MODE) == 0) {                                                       \
      _Pragma("unroll") for (int r = 0; r < 4; ++r) {                        \
        u16x8 p;                                                             \
        p[0] = f2bf(a4[r][0].x); p[1] = f2bf(a4[r][0].y);                    \
        p[2] = f2bf(a4[r][0].z); p[3] = f2bf(a4[r][0].w);                    \
        p[4] = f2bf(a4[r][1].x); p[5] = f2bf(a4[r][1].y);                    \
        p[6] = f2bf(a4[r][1].z); p[7] = f2bf(a4[r][1].w);                    \
        *(u16x8*)&As[(BF) ^ 1][aHh[r]][aLds[r]] = p;                         \
      }                                                                      \
    }                                                                        \
    LGKM_BAR();                                                              \
    __builtin_amdgcn_s_setprio(1);                                           \
    MM_QUAD(1, 0); MM_QUAD(1, 1);                                            \
    __builtin_amdgcn_s_setprio(0);                                           \
    if ((MODE) == 0) {                                                       \
      asm volatile("s_waitcnt vmcnt(0)" ::: "memory");                       \
      LGKM_BAR();                                                            \
    }                                                                        \
  } while (0)

  // prologue: A(0) load->cvt->write, B(0) DMA; full drain once.
  {
    float4 a4[4][2];
#pragma unroll
    for (int r = 0; r < 4; ++r) {
      a4[r][0] = *(const float4*)(aSrc[r]);
      a4[r][1] = *(const float4*)(aSrc[r] + 4);
    }
    STG_B2(0, 0, 0);
    STG_B2(0, 1, 0);
#pragma unroll
    for (int r = 0; r < 4; ++r) {
      u16x8 p;
      p[0] = f2bf(a4[r][0].x); p[1] = f2bf(a4[r][0].y);
      p[2] = f2bf(a4[r][0].z); p[3] = f2bf(a4[r][0].w);
      p[4] = f2bf(a4[r][1].x); p[5] = f2bf(a4[r][1].y);
      p[6] = f2bf(a4[r][1].z); p[7] = f2bf(a4[r][1].w);
      *(u16x8*)&As[0][aHh[r]][aLds[r]] = p;
    }
    asm volatile("s_waitcnt vmcnt(0) lgkmcnt(0)" ::: "memory");
    __builtin_amdgcn_s_barrier();
  }

#pragma unroll 1
  for (int it = 0; it < 16; ++it) {
    TILE(0, 2 * it, 0);
    if (it < 15) {
      TILE(1, 2 * it + 1, 0);
    } else {
      TILE(1, 31, 1);
    }
  }

  // ---- slim epilogue: hoisted invariants, <=3-batch ph select, LDS reduce ----
  const int gnb = n0 + wc * 64 + fr;
  float wa[4], bsv[4], p0[4], p1[4], p2[4];
  const int b0 = m0 / L_;
  const int s1 = (b0 + 1) * L_, s2 = (b0 + 2) * L_;
  const int b1 = (b0 + 1 > 63) ? 63 : b0 + 1;
  const int b2 = (b0 + 2 > 63) ? 63 : b0 + 2;
#pragma unroll
  for (int ni = 0; ni < 4; ++ni) {
    const int gn = gnb + ni * 16;
    wa[ni] = walpha[gn];
    bsv[ni] = batt[gn] + bh[gn];
    p0[ni] = ph[(size_t)b0 * A_ + gn];
    p1[ni] = ph[(size_t)b1 * A_ + gn];
    p2[ni] = ph[(size_t)b2 * A_ + gn];
  }
  __syncthreads();  // all tile reads done before reusing As as scratch
  float (*redp)[128][4] = (float (*)[128][4])As;
#pragma unroll
  for (int mi = 0; mi < 8; ++mi) {
#pragma unroll
    for (int rr = 0; rr < 4; ++rr) {
      const int lr = mi * 16 + fq * 4 + rr;
      const int gm = m0 + wr * 128 + lr;
      float sp = 0.f;
#pragma unroll
      for (int ni = 0; ni < 4; ++ni) {
        const float pv = (gm >= s2) ? p2[ni] : ((gm >= s1) ? p1[ni] : p0[ni]);
        const float p = acc[mi][ni][rr] + pv + bsv[ni];
        sp += tanh_fast(p) * wa[ni];
      }
      sp += __shfl_xor(sp, 1);
      sp += __shfl_xor(sp, 2);
      sp += __shfl_xor(sp, 4);
      sp += __shfl_xor(sp, 8);
      if (fr == 0) redp[wr][lr][wc] = sp;
    }
  }
  __syncthreads();
  if (tid < 256) {
    f32x4 v = ((const f32x4*)redp)[tid];
    scores4[(size_t)(n0 >> 8) * M_ + m0 + tid] = v[0] + v[1] + v[2] + v[3];
  }
}

// ---- fused softmax + weighted sum (fp32 af) ----
__global__ __launch_bounds__(256) void wsum_sm_k(const float* __restrict__ af,
                                                 const float* __restrict__ s4,
                                                 float* __restrict__ out) {
  __shared__ float wl[256];
  __shared__ f32x4 part[256];
  __shared__ float red[4];
  const int b = blockIdx.y;
  const int t = threadIdx.x;

  // softmax over L=196
  float s = -1e30f;
  if (t < L_) {
    const int i = b * L_ + t;
    s = s4[i] + s4[M_ + i] + s4[2 * M_ + i] + s4[3 * M_ + i];
  }
  float m = s;
#pragma unroll
  for (int o = 32; o; o >>= 1) m = fmaxf(m, __shfl_xor(m, o));
  if ((t & 63) == 0) red[t >> 6] = m;
  __syncthreads();
  m = fmaxf(fmaxf(red[0], red[1]), fmaxf(red[2], red[3]));
  float e = (t < L_) ? __expf(s - m) : 0.f;
  float sum = e;
#pragma unroll
  for (int o = 32; o; o >>= 1) sum += __shfl_xor(sum, o);
  __syncthreads();
  if ((t & 63) == 0) red[t >> 6] = sum;
  __syncthreads();
  sum = red[0] + red[1] + red[2] + red[3];
  const float w = e / sum;
  wl[t] = w;
  if (t < L_ && blockIdx.x == 0) out[(size_t)B_ * D_ + b * L_ + t] = w;
  __syncthreads();

  // weighted sum over L for 64 float4-columns per block
  const int lq = t >> 6;
  const int dl = t & 63;
  const int d4 = blockIdx.x * 64 + dl;  // 0..511 float4 groups
  f32x4 acc = {0.f, 0.f, 0.f, 0.f};
  for (int l = lq * 49; l < lq * 49 + 49; ++l) {
    f32x4 v = *(const f32x4*)(af + (size_t)(b * L_ + l) * D_ + d4 * 4);
    acc += v * wl[l];
  }
  part[t] = acc;
  __syncthreads();
  if (t < 64) {
    f32x4 tot = part[t] + part[64 + t] + part[128 + t] + part[192 + t];
    *(f32x4*)(out + (size_t)b * D_ + d4 * 4) = tot;
  }
}

extern "C" void kernel_launch(void* const* d_in, const int* in_sizes, int n_in,
                              void* d_out, int out_size, void* d_ws, size_t ws_size,
                              hipStream_t stream) {
  const float* af    = (const float*)d_in[0];
  const float* h     = (const float*)d_in[1];
  const float* W_att = (const float*)d_in[2];
  const float* b_att = (const float*)d_in[3];
  const float* W_h   = (const float*)d_in[4];
  const float* b_h   = (const float*)d_in[5];
  const float* w_al  = (const float*)d_in[6];
  float* out = (float*)d_out;
  char* ws = (char*)d_ws;

  u16* WT        = (u16*)ws;                       // 4 MB
  float* ph      = (float*)(ws + 0x400000);        // 256 KB
  float* scores4 = (float*)(ws + 0x440000);        // 4 x 12544 fp32 = 200 KB

  hipMemsetAsync(ph, 0, 256u << 10, stream);
  prep_k<<<2304, 256, 0, stream>>>(W_att, WT, h, W_h, ph);
  gemm8_k<<<196, 512, 0, stream>>>(af, WT, ph, b_att, b_h, w_al, scores4);
  wsum_sm_k<<<dim3(8, 64), 256, 0, stream>>>(af, scores4, out);
}

// Round 11
// 118.644 us; speedup vs baseline: 2.9805x; 2.9805x over previous
//
#include <hip/hip_runtime.h>

// Attention_22325240004782 — additive attention. B=64, L=196, D=2048, A=1024.
// R11: R6 (best, 119.2us) with ONE change: PH_PRE no longer force-drains
// lgkmcnt(0); compiler emits fine-grained lgkmcnt at MFMA use sites, letting
// ds_read latency hide under the MFMA cluster. All barrier windows unchanged.
// (R8/R10 lesson: 512thr=2 waves/SIMD caps 256 unified regs/wave; acc=128
// AGPR + 128 VGPR is exactly at cap — no headroom for fused staging.)

typedef unsigned short u16;
typedef u16 u16x8 __attribute__((ext_vector_type(8)));
typedef __bf16 bf16x8 __attribute__((ext_vector_type(8)));
typedef float f32x4 __attribute__((ext_vector_type(4)));

#define B_ 64
#define L_ 196
#define D_ 2048
#define A_ 1024
#define M_ (B_ * L_)  // 12544 = 49 * 256

__device__ __forceinline__ u16 f2bf(float x) {
  unsigned u = __float_as_uint(x);
  unsigned r = (u + 0x7fffu + ((u >> 16) & 1u)) >> 16;  // RNE
  return (u16)r;
}

__device__ __forceinline__ float tanh_fast(float x) {
  float e = __expf(2.0f * x);
  return 1.0f - 2.0f / (e + 1.0f);
}

__device__ __forceinline__ void gload_lds16(const void* g, void* l) {
  __builtin_amdgcn_global_load_lds(
      (const __attribute__((address_space(1))) void*)g,
      (__attribute__((address_space(3))) void*)l, 16, 0, 0);
}

// ---- fused prep: [0,256) ph split-K | [256,2304) W_att transpose |
//                  [2304,4352) af->bf16. Latency-bound blocks first. ----
__global__ __launch_bounds__(256) void prep_k(
    const float* __restrict__ af, u16* __restrict__ afb,
    const float* __restrict__ W, u16* __restrict__ WT,
    const float* __restrict__ h, const float* __restrict__ Wh,
    float* __restrict__ ph) {
  __shared__ float smem[2112];
  const int bid = blockIdx.x;
  const int t = threadIdx.x;
  if (bid < 256) {  // ph split-K (256-iter inner loop, atomics)
    const int ag = bid & 3, bg = (bid >> 2) & 7, dc = bid >> 5;
    const int d0 = dc * 256;
    for (int i = t; i < 2048; i += 256)
      smem[i] = h[(size_t)(bg * 8 + (i >> 8)) * D_ + d0 + (i & 255)];
    __syncthreads();
    const int a = ag * 256 + t;
    float acc[8] = {};
#pragma unroll 8
    for (int d = 0; d < 256; ++d) {
      float wv = Wh[(size_t)(d0 + d) * A_ + a];
#pragma unroll
      for (int bb = 0; bb < 8; ++bb) acc[bb] += smem[bb * 256 + d] * wv;
    }
#pragma unroll
    for (int bb = 0; bb < 8; ++bb)
      atomicAdd(&ph[(size_t)(bg * 8 + bb) * A_ + a], acc[bb]);
  } else if (bid < 2304) {  // W_att [D][A] -> WT [A][D] bf16
    const int tb = bid - 256;
    const int n0 = (tb & 31) * 32, k0 = (tb >> 5) * 32;
    const int tx = t & 31, ty = t >> 5;
    float (*tt)[33] = (float (*)[33])smem;
#pragma unroll
    for (int i = 0; i < 4; ++i)
      tt[ty + i * 8][tx] = W[(size_t)(k0 + ty + i * 8) * A_ + n0 + tx];
    __syncthreads();
#pragma unroll
    for (int i = 0; i < 4; ++i)
      WT[(size_t)(n0 + ty + i * 8) * D_ + k0 + tx] = f2bf(tt[tx][ty + i * 8]);
  } else {  // af fp32 -> bf16 (BW-bound, backfills)
    const int cb = bid - 2304;
    const size_t n = (size_t)M_ * D_;
    for (size_t e = ((size_t)cb * 256 + t) * 8; e < n;
         e += (size_t)2048 * 256 * 8) {
      float4 v0 = *(const float4*)(af + e);
      float4 v1 = *(const float4*)(af + e + 4);
      u16x8 p;
      p[0] = f2bf(v0.x); p[1] = f2bf(v0.y); p[2] = f2bf(v0.z); p[3] = f2bf(v0.w);
      p[4] = f2bf(v1.x); p[5] = f2bf(v1.y); p[6] = f2bf(v1.z); p[7] = f2bf(v1.w);
      *(u16x8*)(afb + e) = p;
    }
  }
}

// ==== 256x256x(BK=64) merged-2-phase GEMM with fused tanh-score epilogue ====
// 512 thr = 8 waves (2M x 4N). Wave output 128x64. LDS 128 KiB. st_16x32
// swizzle (0 conflicts). Counted vmcnt(6); setprio on MFMA. 5 barriers/K-tile.
// ds_read->MFMA waits are compiler-inserted fine-grained lgkmcnt (no manual
// drain) — the phase barriers alone enforce the cross-wave write windows.
__global__ __launch_bounds__(512, 2) void gemm8_k(
    const u16* __restrict__ afb, const u16* __restrict__ WT,
    const float* __restrict__ ph, const float* __restrict__ batt,
    const float* __restrict__ bh, const float* __restrict__ walpha,
    float* __restrict__ scores4) {
  __shared__ __align__(16) u16 As[2][2][8192];
  __shared__ __align__(16) u16 Bs[2][2][8192];
  const int tid = threadIdx.x;
  const int lane = tid & 63;
  const int wid = tid >> 6;
  const int wr = wid >> 2;   // 0..1 (M)
  const int wc = wid & 3;    // 0..3 (N)
  const int wchalf = wc >> 1, wcl = wc & 1;
  const int fr = lane & 15, fq = lane >> 4;

  // bijective XCD remap: 196 blocks, q=24, r=4
  const int xcd = blockIdx.x & 7, idx = blockIdx.x >> 3;
  const int wg = (xcd < 4 ? xcd * 25 : 100 + (xcd - 4) * 24) + idx;
  const int m0 = (wg >> 2) * 256;
  const int n0 = (wg & 3) * 256;

  // staging geometry (pre-swizzled global source, linear LDS dest)
  int rowc[2], colc[2];
#pragma unroll
  for (int r = 0; r < 2; ++r) {
    int c = r * 512 + tid;
    int s = c >> 6, cw = c & 63;
    rowc[r] = (s >> 1) * 16 + (cw >> 2);
    colc[r] = (s & 1) * 32 + ((((cw & 3) * 16) ^ (((cw >> 5) & 1) * 32)) >> 1);
  }
  const u16* srcA[2][2];
  const u16* srcB[2][2];
#pragma unroll
  for (int hh = 0; hh < 2; ++hh)
#pragma unroll
    for (int r = 0; r < 2; ++r) {
      srcA[hh][r] = afb + (size_t)(m0 + hh * 128 + rowc[r]) * D_ + colc[r];
      srcB[hh][r] = WT + (size_t)(n0 + hh * 128 + rowc[r]) * D_ + colc[r];
    }

  // swizzled lane byte offset for ds_read_b128 fragment reads
  const int laneA = (lane & 15) * 64 + (((lane >> 4) * 16) ^ ((lane & 8) << 2));

  f32x4 acc[8][4] = {};
  u16x8 areg[4][2], breg[4][2];

#define STG_A(BUF, H, KT)                                                    \
  do {                                                                       \
    gload_lds16(srcA[H][0] + (size_t)(KT) * 64, &As[BUF][H][wid * 512]);     \
    gload_lds16(srcA[H][1] + (size_t)(KT) * 64, &As[BUF][H][4096 + wid * 512]); \
  } while (0)
#define STG_B(BUF, H, KT)                                                    \
  do {                                                                       \
    gload_lds16(srcB[H][0] + (size_t)(KT) * 64, &Bs[BUF][H][wid * 512]);     \
    gload_lds16(srcB[H][1] + (size_t)(KT) * 64, &Bs[BUF][H][4096 + wid * 512]); \
  } while (0)
#define LDA_HALF(BF, MH)                                                     \
  do {                                                                       \
    _Pragma("unroll") for (int q = 0; q < 4; ++q) {                          \
      areg[q][0] = *(const u16x8*)&As[BF][wr][((((MH)*4 + q) * 2 + 0) * 1024 + laneA) >> 1]; \
      areg[q][1] = *(const u16x8*)&As[BF][wr][((((MH)*4 + q) * 2 + 1) * 1024 + laneA) >> 1]; \
    }                                                                        \
  } while (0)
#define LDB_PAIR(BF, NQ)                                                     \
  do {                                                                       \
    _Pragma("unroll") for (int nn = 0; nn < 2; ++nn) {                       \
      breg[(NQ)*2 + nn][0] = *(const u16x8*)&Bs[BF][wchalf][(((wcl * 4 + (NQ)*2 + nn) * 2 + 0) * 1024 + laneA) >> 1]; \
      breg[(NQ)*2 + nn][1] = *(const u16x8*)&Bs[BF][wchalf][(((wcl * 4 + (NQ)*2 + nn) * 2 + 1) * 1024 + laneA) >> 1]; \
    }                                                                        \
  } while (0)
#define MM_QUAD(MH, NQ)                                                      \
  do {                                                                       \
    _Pragma("unroll") for (int q = 0; q < 4; ++q)                            \
    _Pragma("unroll") for (int nn = 0; nn < 2; ++nn)                         \
    _Pragma("unroll") for (int kh = 0; kh < 2; ++kh)                         \
      acc[(MH)*4 + q][(NQ)*2 + nn] = __builtin_amdgcn_mfma_f32_16x16x32_bf16( \
          __builtin_bit_cast(bf16x8, areg[q][kh]),                           \
          __builtin_bit_cast(bf16x8, breg[(NQ)*2 + nn][kh]),                 \
          acc[(MH)*4 + q][(NQ)*2 + nn], 0, 0, 0);                            \
  } while (0)
// R11: no manual lgkm drain — compiler inserts fine-grained lgkmcnt at the
// first MFMA use of each ds_read result. Barrier windows preserved: a wave
// reaches a phase's closing barrier only after its MFMAs (and thus all its
// lgkm waits) retire, so post-barrier DMA writes cannot race the reads.
#define PH_PRE()                                                             \
  do {                                                                       \
    __builtin_amdgcn_s_barrier();                                            \
    __builtin_amdgcn_s_setprio(1);                                           \
  } while (0)
#define PH_POST()                                                            \
  do {                                                                       \
    __builtin_amdgcn_s_setprio(0);                                           \
    __builtin_amdgcn_s_barrier();                                            \
  } while (0)
// Merged 2-phase K-tile. Per-wave FIFO: 8 loads/tile issued; end-of-tile
// vmcnt(6) retires exactly the NEXT tile's 4 half-tiles (enter tile t with
// {t+1.B0,B1,A0} outstanding).
#define KTILE(BF, T, MODE)                                                   \
  do {                                                                       \
    LDA_HALF(BF, 0); LDB_PAIR(BF, 0); LDB_PAIR(BF, 1);                       \
    if ((MODE) <= 1) STG_A((BF) ^ 1, 1, (T) + 1);                            \
    PH_PRE(); MM_QUAD(0, 0); MM_QUAD(0, 1); PH_POST();                       \
    LDA_HALF(BF, 1);                                                         \
    if ((MODE) == 0) { STG_B(BF, 0, (T) + 2); STG_B(BF, 1, (T) + 2);         \
                       STG_A(BF, 0, (T) + 2); }                              \
    PH_PRE(); MM_QUAD(1, 0); MM_QUAD(1, 1);                                  \
    __builtin_amdgcn_s_setprio(0);                                           \
    if ((MODE) == 0) asm volatile("s_waitcnt vmcnt(6)" ::: "memory");        \
    if ((MODE) == 1) asm volatile("s_waitcnt vmcnt(0)" ::: "memory");        \
    if ((MODE) <= 1) __builtin_amdgcn_s_barrier();                           \
  } while (0)

  // prologue: tile0 all 4 half-tiles + tile1 {B0,B1,A0}
  STG_B(0, 0, 0); STG_B(0, 1, 0); STG_A(0, 0, 0); STG_A(0, 1, 0);
  STG_B(1, 0, 1); STG_B(1, 1, 1); STG_A(1, 0, 1);
  asm volatile("s_waitcnt vmcnt(6)" ::: "memory");
  __builtin_amdgcn_s_barrier();

#pragma unroll 1
  for (int it = 0; it < 15; ++it) {
    const int t = it * 2;
    KTILE(0, t, 0);
    KTILE(1, t + 1, 0);
  }
  KTILE(0, 30, 1);
  KTILE(1, 31, 2);

  // ---- slim epilogue: hoisted invariants, <=3-batch ph select, LDS reduce ----
  const int gnb = n0 + wc * 64 + fr;
  float wa[4], bsv[4], p0[4], p1[4], p2[4];
  const int b0 = m0 / L_;
  const int s1 = (b0 + 1) * L_, s2 = (b0 + 2) * L_;
  const int b1 = (b0 + 1 > 63) ? 63 : b0 + 1;
  const int b2 = (b0 + 2 > 63) ? 63 : b0 + 2;
#pragma unroll
  for (int ni = 0; ni < 4; ++ni) {
    const int gn = gnb + ni * 16;
    wa[ni] = walpha[gn];
    bsv[ni] = batt[gn] + bh[gn];
    p0[ni] = ph[(size_t)b0 * A_ + gn];
    p1[ni] = ph[(size_t)b1 * A_ + gn];
    p2[ni] = ph[(size_t)b2 * A_ + gn];
  }
  __syncthreads();  // full drain before reusing As as reduce scratch
  float (*redp)[128][4] = (float (*)[128][4])As;
#pragma unroll
  for (int mi = 0; mi < 8; ++mi) {
#pragma unroll
    for (int rr = 0; rr < 4; ++rr) {
      const int lr = mi * 16 + fq * 4 + rr;
      const int gm = m0 + wr * 128 + lr;
      float sp = 0.f;
#pragma unroll
      for (int ni = 0; ni < 4; ++ni) {
        const float pv = (gm >= s2) ? p2[ni] : ((gm >= s1) ? p1[ni] : p0[ni]);
        const float p = acc[mi][ni][rr] + pv + bsv[ni];
        sp += tanh_fast(p) * wa[ni];
      }
      sp += __shfl_xor(sp, 1);
      sp += __shfl_xor(sp, 2);
      sp += __shfl_xor(sp, 4);
      sp += __shfl_xor(sp, 8);
      if (fr == 0) redp[wr][lr][wc] = sp;
    }
  }
  __syncthreads();
  if (tid < 256) {
    f32x4 v = ((const f32x4*)redp)[tid];
    scores4[(size_t)(n0 >> 8) * M_ + m0 + tid] = v[0] + v[1] + v[2] + v[3];
  }
}

// ---- fused softmax + weighted sum (bf16 af) ----
__global__ __launch_bounds__(256) void wsum_sm_k(const u16* __restrict__ afb,
                                                 const float* __restrict__ s4,
                                                 float* __restrict__ out) {
  __shared__ float wl[256];
  __shared__ float part[256][8];
  __shared__ float red[4];
  const int b = blockIdx.y;
  const int t = threadIdx.x;

  // softmax over L=196
  float s = -1e30f;
  if (t < L_) {
    const int i = b * L_ + t;
    s = s4[i] + s4[M_ + i] + s4[2 * M_ + i] + s4[3 * M_ + i];
  }
  float m = s;
#pragma unroll
  for (int o = 32; o; o >>= 1) m = fmaxf(m, __shfl_xor(m, o));
  if ((t & 63) == 0) red[t >> 6] = m;
  __syncthreads();
  m = fmaxf(fmaxf(red[0], red[1]), fmaxf(red[2], red[3]));
  float e = (t < L_) ? __expf(s - m) : 0.f;
  float sum = e;
#pragma unroll
  for (int o = 32; o; o >>= 1) sum += __shfl_xor(sum, o);
  __syncthreads();
  if ((t & 63) == 0) red[t >> 6] = sum;
  __syncthreads();
  sum = red[0] + red[1] + red[2] + red[3];
  const float w = e / sum;
  wl[t] = w;
  if (t < L_ && blockIdx.x == 0) out[(size_t)B_ * D_ + b * L_ + t] = w;
  __syncthreads();

  // weighted sum over L for 512 d-columns (64 lanes x 8 elems)
  const int lq = t >> 6;
  const int dl = t & 63;
  const int d8 = blockIdx.x * 64 + dl;
  float acc[8] = {};
  for (int l = lq * 49; l < lq * 49 + 49; ++l) {
    u16x8 v = *(const u16x8*)(afb + (size_t)(b * L_ + l) * D_ + d8 * 8);
    float ww = wl[l];
#pragma unroll
    for (int j = 0; j < 8; ++j)
      acc[j] += ww * __uint_as_float((unsigned)v[j] << 16);
  }
#pragma unroll
  for (int j = 0; j < 8; ++j) part[t][j] = acc[j];
  __syncthreads();
  if (t < 64) {
    float4 o0, o1;
    o0.x = part[dl][0] + part[64 + dl][0] + part[128 + dl][0] + part[192 + dl][0];
    o0.y = part[dl][1] + part[64 + dl][1] + part[128 + dl][1] + part[192 + dl][1];
    o0.z = part[dl][2] + part[64 + dl][2] + part[128 + dl][2] + part[192 + dl][2];
    o0.w = part[dl][3] + part[64 + dl][3] + part[128 + dl][3] + part[192 + dl][3];
    o1.x = part[dl][4] + part[64 + dl][4] + part[128 + dl][4] + part[192 + dl][4];
    o1.y = part[dl][5] + part[64 + dl][5] + part[128 + dl][5] + part[192 + dl][5];
    o1.z = part[dl][6] + part[64 + dl][6] + part[128 + dl][6] + part[192 + dl][6];
    o1.w = part[dl][7] + part[64 + dl][7] + part[128 + dl][7] + part[192 + dl][7];
    *(float4*)(out + (size_t)b * D_ + d8 * 8) = o0;
    *(float4*)(out + (size_t)b * D_ + d8 * 8 + 4) = o1;
  }
}

extern "C" void kernel_launch(void* const* d_in, const int* in_sizes, int n_in,
                              void* d_out, int out_size, void* d_ws, size_t ws_size,
                              hipStream_t stream) {
  const float* af    = (const float*)d_in[0];
  const float* h     = (const float*)d_in[1];
  const float* W_att = (const float*)d_in[2];
  const float* b_att = (const float*)d_in[3];
  const float* W_h   = (const float*)d_in[4];
  const float* b_h   = (const float*)d_in[5];
  const float* w_al  = (const float*)d_in[6];
  float* out = (float*)d_out;
  char* ws = (char*)d_ws;

  u16* afb       = (u16*)ws;                       // 51.4 MB
  u16* WT        = (u16*)(ws + 0x3200000);         // 4 MB
  float* ph      = (float*)(ws + 0x3600000);       // 256 KB
  float* scores4 = (float*)(ws + 0x3640000);       // 4 x 12544 fp32 = 200 KB

  hipMemsetAsync(ph, 0, 256u << 10, stream);
  prep_k<<<4352, 256, 0, stream>>>(af, afb, W_att, WT, h, W_h, ph);
  gemm8_k<<<196, 512, 0, stream>>>(afb, WT, ph, b_att, b_h, w_al, scores4);
  wsum_sm_k<<<dim3(4, 64), 256, 0, stream>>>(afb, scores4, out);
}